// Round 10
// baseline (61.710 us; speedup 1.0000x reference)
//
#include <hip/hip_runtime.h>
#include <hip/hip_cooperative_groups.h>

#define NPTS   2048
#define NROWS  (2 * NPTS)        // 4096
#define CCH    32
#define VOL_V  (64 * 128 * 128)  // 1048576
#define INV_T  (1.0f / 0.07f)
#define SCALE  (INV_T * 1.4426950408889634f)   // 1/(T*ln2): exp(s/T)=exp2(s*SCALE)

typedef __attribute__((ext_vector_type(8))) short bf16x8;  // 8 bf16 = 4 VGPRs
typedef __attribute__((ext_vector_type(4))) float f32x4;

// ---------------------------------------------------------------------------
// Single cooperative kernel: phase 1 gathers E_bf (and zeroes d_out), then
// grid.sync(), then phase 2 = fused rowsum+finalize (byte-identical to the
// round-8 rowsum body, absmax 0.0 verified rounds 3/5/7/8/9).
// Grid: 256 blocks x 1024 threads = 1 block/CU on 256 CUs (co-resident).
// ---------------------------------------------------------------------------
__global__ __launch_bounds__(1024) void fused_k(
    const float* __restrict__ e0, const float* __restrict__ e1,
    const float* __restrict__ loc0, const float* __restrict__ loc1,
    unsigned short* __restrict__ Eb, float* __restrict__ out)
{
    // ---- phase 1: gather ------------------------------------------------
    int gidx = blockIdx.x * 1024 + threadIdx.x;   // 0 .. 262143
    if (gidx == 0) out[0] = 0.0f;                 // pre-sync: ordered before atomics
    if (gidx < NROWS * CCH) {
        int r = gidx >> 5;
        int c = gidx & 31;
        const float* loc = (r < NPTS) ? (loc0 + 3 * r) : (loc1 + 3 * (r - NPTS));
        const float* e   = (r < NPTS) ? e0 : e1;
        int ind = (int)loc[0] * 16384 + (int)loc[1] * 128 + (int)loc[2];
        float v = __builtin_nontemporal_load(e + (size_t)c * VOL_V + ind);
        unsigned u = __builtin_bit_cast(unsigned, v);
        u += 0x7fff + ((u >> 16) & 1);            // RNE to bf16
        Eb[gidx] = (unsigned short)(u >> 16);
    }

    cooperative_groups::this_grid().sync();

    // ---- phase 2: rowsum + finalize (R8 body) ---------------------------
    int lane = threadIdx.x & 63;
    int w    = threadIdx.x >> 6;        // 0..15: j-chunk of this wave
    int bid  = blockIdx.x;
    int r0   = bid * 16;                // this block's row stripe
    int lrow = lane & 15;
    int lgrp = lane >> 4;               // 0..3
    int koff = lgrp * 8;                // k-offset of this lane's 8 bf16

    bf16x8 a = *(const bf16x8*)(Eb + (size_t)(r0 + lrow) * CCH + koff);

    float racc[4]  = {0.f, 0.f, 0.f, 0.f};
    float pairv[4] = {0.f, 0.f, 0.f, 0.f};
    int rg = r0 + lgrp * 4;             // global row of acc[q] - q

    const f32x4 zero = {0.f, 0.f, 0.f, 0.f};
    int diag_t = bid;                   // tile holding S[r][r]
    int pair_t = bid ^ (NPTS / 16);     // tile holding S[r][r^NPTS]

    #pragma unroll 4
    for (int t = 0; t < 16; ++t) {
        int tg = w * 16 + t;            // global tile index (wave-uniform)
        int j0 = tg * 16;
        bf16x8 b = *(const bf16x8*)(Eb + (size_t)(j0 + lrow) * CCH + koff);
        f32x4 c = __builtin_amdgcn_mfma_f32_16x16x32_bf16(a, b, zero, 0, 0, 0);
        if (tg == diag_t || tg == pair_t) {          // wave-uniform branch
            int jg = j0 + lrow;
            #pragma unroll
            for (int q = 0; q < 4; ++q) {
                float ex = exp2f(c[q] * SCALE);
                racc[q] += (jg == rg + q) ? 0.0f : ex;                   // skip diag
                pairv[q] = (jg == ((rg + q) ^ NPTS)) ? c[q] : pairv[q];  // s_pair
            }
        } else {                                      // fast path: 254/256 tiles
            #pragma unroll
            for (int q = 0; q < 4; ++q)
                racc[q] += exp2f(c[q] * SCALE);
        }
    }

    // reduce across the 16 B-row lanes (columns of the tile)
    #pragma unroll
    for (int q = 0; q < 4; ++q) {
        #pragma unroll
        for (int m = 1; m < 16; m <<= 1) {
            racc[q]  += __shfl_xor(racc[q], m);
            pairv[q] += __shfl_xor(pairv[q], m);   // exactly one nonzero lane
        }
    }

    __shared__ float lds_rs[16][16];
    __shared__ float lds_ps[16][16];
    if (lrow == 0) {
        #pragma unroll
        for (int q = 0; q < 4; ++q) {
            lds_rs[w][lgrp * 4 + q] = racc[q];
            lds_ps[w][lgrp * 4 + q] = pairv[q];
        }
    }
    __syncthreads();

    if (threadIdx.x < 16) {
        int row = threadIdx.x;
        float rs = 0.f, ps = 0.f;
        #pragma unroll
        for (int ww = 0; ww < 16; ++ww) {
            rs += lds_rs[ww][row];
            ps += lds_ps[ww][row];
        }
        float contrib = ps * INV_T - __logf(rs);
        #pragma unroll
        for (int m = 1; m < 16; m <<= 1)
            contrib += __shfl_xor(contrib, m);
        if (row == 0)
            atomicAdd(out, -contrib / (2.0f * NPTS));
    }
}

// ---------------------------------------------------------------------------
extern "C" void kernel_launch(void* const* d_in, const int* in_sizes, int n_in,
                              void* d_out, int out_size, void* d_ws, size_t ws_size,
                              hipStream_t stream)
{
    const float* e0 = (const float*)d_in[0];
    const float* e1 = (const float*)d_in[1];
    const float* l0 = (const float*)d_in[2];
    const float* l1 = (const float*)d_in[3];
    float* out = (float*)d_out;

    unsigned short* Eb = (unsigned short*)d_ws;   // 256 KB

    void* args[] = {(void*)&e0, (void*)&e1, (void*)&l0, (void*)&l1,
                    (void*)&Eb, (void*)&out};
    hipLaunchCooperativeKernel((const void*)fused_k, dim3(NROWS / 16),
                               dim3(1024), args, 0, stream);
}

// Round 11
// 21.660 us; speedup vs baseline: 2.8491x; 2.8491x over previous
//
#include <hip/hip_runtime.h>

#define NPTS   2048
#define NROWS  (2 * NPTS)        // 4096
#define CCH    32
#define VOL_V  (64 * 128 * 128)  // 1048576
#define INV_T  (1.0f / 0.07f)
#define SCALE  (INV_T * 1.4426950408889634f)   // 1/(T*ln2): exp(s/T)=exp2(s*SCALE)

typedef __attribute__((ext_vector_type(8))) short bf16x8;  // 8 bf16 = 4 VGPRs
typedef __attribute__((ext_vector_type(4))) float f32x4;

// ---------------------------------------------------------------------------
// K1: gather E_bf[r][c] = bf16(emb[c*V + ind(r)]); zero d_out (stream-ordered
// before K2's atomics; re-zeroed every launch => graph replays deterministic).
// Volume reads are single-use -> nontemporal to keep L2 for Eb.
// ---------------------------------------------------------------------------
__global__ __launch_bounds__(256) void gather_k(
    const float* __restrict__ e0, const float* __restrict__ e1,
    const float* __restrict__ loc0, const float* __restrict__ loc1,
    unsigned short* __restrict__ Eb, float* __restrict__ out)
{
    int idx = blockIdx.x * 256 + threadIdx.x;   // 0 .. NROWS*CCH-1
    if (idx == 0) out[0] = 0.0f;
    if (idx >= NROWS * CCH) return;
    int r = idx >> 5;
    int c = idx & 31;
    const float* loc = (r < NPTS) ? (loc0 + 3 * r) : (loc1 + 3 * (r - NPTS));
    const float* e   = (r < NPTS) ? e0 : e1;
    int ind = (int)loc[0] * 16384 + (int)loc[1] * 128 + (int)loc[2];
    float v = __builtin_nontemporal_load(e + (size_t)c * VOL_V + ind);
    unsigned u = __builtin_bit_cast(unsigned, v);
    u += 0x7fff + ((u >> 16) & 1);              // RNE to bf16
    Eb[idx] = (unsigned short)(u >> 16);
}

// ---------------------------------------------------------------------------
// K2: fused rowsum + finalize, block-local only (no device fences — grid-wide
// sync/fence costs 30-40us on gfx950's non-coherent XCD L2s; measured R4/R10).
// Each block owns one 16-row stripe; its 16 waves (1024 thr) split the 256
// j-tiles (16 each) => 4096 waves = 4/SIMD chip-wide.
// Wave-uniform tile specialization: diagonal only in tile bid, pair column
// only in tile bid^128; other 254 tiles take a compare-free fast path.
// acc[q] layout (verified rounds 3/5/7/8/9, absmax 0.0): S[A-row=lgrp*4+q][B-row=lrow].
// ---------------------------------------------------------------------------
__global__ __launch_bounds__(1024) void rowsum_k(
    const unsigned short* __restrict__ Eb, float* __restrict__ out)
{
    int lane = threadIdx.x & 63;
    int w    = threadIdx.x >> 6;        // 0..15: j-chunk of this wave
    int bid  = blockIdx.x;
    int r0   = bid * 16;                // this block's row stripe
    int lrow = lane & 15;
    int lgrp = lane >> 4;               // 0..3
    int koff = lgrp * 8;                // k-offset of this lane's 8 bf16

    bf16x8 a = *(const bf16x8*)(Eb + (size_t)(r0 + lrow) * CCH + koff);

    float racc[4]  = {0.f, 0.f, 0.f, 0.f};
    float pairv[4] = {0.f, 0.f, 0.f, 0.f};
    int rg = r0 + lgrp * 4;             // global row of acc[q] - q

    const f32x4 zero = {0.f, 0.f, 0.f, 0.f};
    int diag_t = bid;                   // tile holding S[r][r]
    int pair_t = bid ^ (NPTS / 16);     // tile holding S[r][r^NPTS]

    #pragma unroll 4
    for (int t = 0; t < 16; ++t) {
        int tg = w * 16 + t;            // global tile index (wave-uniform)
        int j0 = tg * 16;
        bf16x8 b = *(const bf16x8*)(Eb + (size_t)(j0 + lrow) * CCH + koff);
        f32x4 c = __builtin_amdgcn_mfma_f32_16x16x32_bf16(a, b, zero, 0, 0, 0);
        if (tg == diag_t || tg == pair_t) {          // wave-uniform branch
            int jg = j0 + lrow;
            #pragma unroll
            for (int q = 0; q < 4; ++q) {
                float ex = exp2f(c[q] * SCALE);
                racc[q] += (jg == rg + q) ? 0.0f : ex;                   // skip diag
                pairv[q] = (jg == ((rg + q) ^ NPTS)) ? c[q] : pairv[q];  // s_pair
            }
        } else {                                      // fast path: 254/256 tiles
            #pragma unroll
            for (int q = 0; q < 4; ++q)
                racc[q] += exp2f(c[q] * SCALE);
        }
    }

    // reduce across the 16 B-row lanes (columns of the tile)
    #pragma unroll
    for (int q = 0; q < 4; ++q) {
        #pragma unroll
        for (int m = 1; m < 16; m <<= 1) {
            racc[q]  += __shfl_xor(racc[q], m);
            pairv[q] += __shfl_xor(pairv[q], m);   // exactly one nonzero lane
        }
    }

    __shared__ float lds_rs[16][16];
    __shared__ float lds_ps[16][16];
    if (lrow == 0) {
        #pragma unroll
        for (int q = 0; q < 4; ++q) {
            lds_rs[w][lgrp * 4 + q] = racc[q];
            lds_ps[w][lgrp * 4 + q] = pairv[q];
        }
    }
    __syncthreads();

    if (threadIdx.x < 16) {
        int row = threadIdx.x;
        float rs = 0.f, ps = 0.f;
        #pragma unroll
        for (int ww = 0; ww < 16; ++ww) {
            rs += lds_rs[ww][row];
            ps += lds_ps[ww][row];
        }
        float contrib = ps * INV_T - __logf(rs);
        #pragma unroll
        for (int m = 1; m < 16; m <<= 1)
            contrib += __shfl_xor(contrib, m);
        if (row == 0)
            atomicAdd(out, -contrib / (2.0f * NPTS));
    }
}

// ---------------------------------------------------------------------------
extern "C" void kernel_launch(void* const* d_in, const int* in_sizes, int n_in,
                              void* d_out, int out_size, void* d_ws, size_t ws_size,
                              hipStream_t stream)
{
    const float* e0 = (const float*)d_in[0];
    const float* e1 = (const float*)d_in[1];
    const float* l0 = (const float*)d_in[2];
    const float* l1 = (const float*)d_in[3];
    float* out = (float*)d_out;

    unsigned short* Eb = (unsigned short*)d_ws;   // 256 KB

    gather_k<<<(NROWS * CCH) / 256, 256, 0, stream>>>(e0, e1, l0, l1, Eb, out);

    rowsum_k<<<NROWS / 16, 1024, 0, stream>>>(Eb, out);  // 256 blocks x 16 waves
}